// Round 15
// baseline (569.988 us; speedup 1.0000x reference)
//
#include <hip/hip_runtime.h>

// ---------------------------------------------------------------------------
// WindowAttention: x[2048,49,512] fp32 -> out[2048,49,512] fp32
// R1: T2 LDS XOR-swizzle + T1 XCD swizzle (bank conflicts -> 0).   [593us]
// R2/R5/R11: GEMM pipeline restructures ALL neutral-or-worse at K=512.
// R3: raw-barrier RACE. R4/R7: fused cvt REGRESSED.
// R6: wave-per-head attention.                                     [575us]
// R8: no-max softmax + ones-MFMA rowsum; token-major qkv.          [573us]
// R9/R10: attn wave-private LDS, no syncthreads, quarter Ps.       [554us]
// R12: maskx float4; scale-in-epilogue branch cost 15us.
// R13: scale folded into W/bias at cvt; attn fence = mem-order only.[542us]
// R14: BK=32 GEMMs (LDS 32->16KB): +1 resident block/CU (VGPR-capped at 6),
//      half the drain latency per barrier, same sync structure/total bytes.
//      New 2-way-free swizzle for 64B rows: key(r)=((r>>2)&3)^((r>>1)&1).
// ---------------------------------------------------------------------------

typedef unsigned short ushort_t;
typedef __bf16 bf16x8 __attribute__((ext_vector_type(8)));
typedef float f32x4 __attribute__((ext_vector_type(4)));
typedef unsigned short us8 __attribute__((ext_vector_type(8)));

#define SCALE_F 0.17677669529663687f   // 32^-0.5

// RNE float -> bf16 (as raw ushort)
__device__ __forceinline__ ushort_t f2bf(float f) {
  unsigned u = __builtin_bit_cast(unsigned, f);
  u += 0x7FFFu + ((u >> 16) & 1u);
  return (ushort_t)(u >> 16);
}

// async global->LDS, 16B per lane; lds base must be wave-uniform
__device__ __forceinline__ void gload_lds16(const void* g, void* l) {
  __builtin_amdgcn_global_load_lds(
      (const __attribute__((address_space(1))) void*)g,
      (__attribute__((address_space(3))) void*)l, 16, 0, 0);
}

// wave-local LDS ordering fence (no sched_barrier: scheduler may overlap)
__device__ __forceinline__ void lds_fence() {
  asm volatile("s_waitcnt lgkmcnt(0)" ::: "memory");
}

// BK=32 swizzle key: 4 chunks/row, 2 bank-parities; key(r) spreads 16 rows
// over 8 slots at exactly 2-way (free). Verified by enumeration.
__device__ __forceinline__ int swzkey(int r) {
  return ((r >> 2) & 3) ^ ((r >> 1) & 1);
}

// ---------------------------------------------------------------------------
// fp32 -> bf16 conversion, 4 elems/thread
// ---------------------------------------------------------------------------
__global__ __launch_bounds__(256) void k_cvt(const float* __restrict__ in,
                                             ushort_t* __restrict__ out, int n4) {
  int i = blockIdx.x * blockDim.x + threadIdx.x;
  if (i >= n4) return;
  float4 v = reinterpret_cast<const float4*>(in)[i];
  ushort4 o = make_ushort4(f2bf(v.x), f2bf(v.y), f2bf(v.z), f2bf(v.w));
  reinterpret_cast<ushort4*>(out)[i] = o;
}

// W_qkv cvt with q-row pre-scale: rows o<512 (elems < 262144) * SCALE_F.
__global__ __launch_bounds__(256) void k_cvtwq(const float* __restrict__ in,
                                               ushort_t* __restrict__ out, int n4) {
  int i = blockIdx.x * blockDim.x + threadIdx.x;
  if (i >= n4) return;
  const float sc = (i < (262144 / 4)) ? SCALE_F : 1.0f;
  float4 v = reinterpret_cast<const float4*>(in)[i];
  ushort4 o = make_ushort4(f2bf(v.x * sc), f2bf(v.y * sc),
                           f2bf(v.z * sc), f2bf(v.w * sc));
  reinterpret_cast<ushort4*>(out)[i] = o;
}

// scaled qkv bias: bs[i] = b[i] * (i<512 ? SCALE : 1). 1536 elems.
__global__ __launch_bounds__(256) void k_bs(const float* __restrict__ b,
                                            float* __restrict__ bs) {
  int i = blockIdx.x * blockDim.x + threadIdx.x;
  if (i < 1536) bs[i] = b[i] * (i < 512 ? SCALE_F : 1.0f);
}

// ---------------------------------------------------------------------------
// mask pre-transpose: maskx[w][qr(64)][arow(16)][ni(4)] f32, pad = -100.
// ---------------------------------------------------------------------------
__global__ __launch_bounds__(256) void k_maskx(const float* __restrict__ mask,
                                               float* __restrict__ maskx) {
  const int i = blockIdx.x * blockDim.x + threadIdx.x;   // < 262144
  const int ni = i & 3, arow = (i >> 2) & 15, qr = (i >> 6) & 63, w = i >> 12;
  const int col = ni * 16 + arow;
  float v = -100.0f;
  if (qr < 49 && col < 49) v = mask[((size_t)w * 49 + qr) * 49 + col];
  maskx[i] = v;
}

// ---------------------------------------------------------------------------
// GEMM, BK=32: C[m][o] = sum_k A[m][k]*W[o][k] + bias[o], K=512, 16 K-steps.
// 128x128 tile, 4 waves, gload_lds staging, 16KB LDS, swzkey swizzle.
// Staging per step: 2 rounds each for A and W; round i covers rows
// i*64 + wv*16 + (lane>>2), slot chunk lane&3, source chunk pre-swizzled.
// EPI=0: token-major qkv bf16 out. EPI=1: fp32 out.
// ---------------------------------------------------------------------------
template <int EPI>
__global__ __launch_bounds__(256) void k_gemm(const ushort_t* __restrict__ A,
                                              const ushort_t* __restrict__ W,
                                              const float* __restrict__ bias,
                                              ushort_t* __restrict__ out_qkv,
                                              float* __restrict__ out_f,
                                              int nt_o) {
  __shared__ __align__(16) ushort_t As[128][32];
  __shared__ __align__(16) ushort_t Ws[128][32];

  const int tid  = threadIdx.x;
  const int lane = tid & 63;
  const int wv   = tid >> 6;
  const int wr   = wv >> 1, wc = wv & 1;

  const int cpx = gridDim.x >> 3;
  const int lid = (blockIdx.x & 7) * cpx + (blockIdx.x >> 3);
  const int bm  = lid / nt_o;
  const int bo  = lid - bm * nt_o;
  const size_t m0 = (size_t)bm * 128;
  const int o0    = bo * 128;

  f32x4 acc[4][4];
#pragma unroll
  for (int i = 0; i < 4; i++)
#pragma unroll
    for (int j = 0; j < 4; j++) acc[i][j] = f32x4{0.f, 0.f, 0.f, 0.f};

  // staging geometry (per gload round): lane covers row (lane>>2), 16 rows
  const int srow = lane >> 2;                          // 0..15 within round
  const int scol = ((lane & 3) ^ swzkey(srow)) * 8;    // pre-swizzled source col

  for (int kt = 0; kt < 16; ++kt) {
    const int k0 = kt * 32;
#pragma unroll
    for (int i = 0; i < 2; i++) {
      const int rb = i * 64 + wv * 16;                 // round row base
      gload_lds16(A + (m0 + rb + srow) * 512 + k0 + scol, &As[rb][0]);
    }
#pragma unroll
    for (int i = 0; i < 2; i++) {
      const int rb = i * 64 + wv * 16;
      gload_lds16(W + (size_t)(o0 + rb + srow) * 512 + k0 + scol, &Ws[rb][0]);
    }
    __syncthreads();
    const int fr = lane & 15;
    const int cb = ((lane >> 4) ^ swzkey(fr)) << 3;    // swizzled elem offset
    uint4 ar[4], br[4];
#pragma unroll
    for (int mi = 0; mi < 4; mi++)
      ar[mi] = *reinterpret_cast<const uint4*>(&As[wr * 64 + mi * 16 + fr][cb]);
#pragma unroll
    for (int ni = 0; ni < 4; ni++)
      br[ni] = *reinterpret_cast<const uint4*>(&Ws[wc * 64 + ni * 16 + fr][cb]);
#pragma unroll
    for (int mi = 0; mi < 4; mi++)
#pragma unroll
      for (int ni = 0; ni < 4; ni++)
        acc[mi][ni] = __builtin_amdgcn_mfma_f32_16x16x32_bf16(
            __builtin_bit_cast(bf16x8, ar[mi]),
            __builtin_bit_cast(bf16x8, br[ni]), acc[mi][ni], 0, 0, 0);
    __syncthreads();
  }

  const int colbase = lane & 15;
  const int rowgrp  = (lane >> 4) * 4;

  if constexpr (EPI == 1) {
#pragma unroll
    for (int ni = 0; ni < 4; ni++) {
      const int o = o0 + wc * 64 + ni * 16 + colbase;
      const float bv = bias[o];
#pragma unroll
      for (int mi = 0; mi < 4; mi++) {
        const size_t mrow = m0 + wr * 64 + mi * 16 + rowgrp;
#pragma unroll
        for (int r = 0; r < 4; r++)
          out_f[(mrow + r) * 512 + o] = acc[mi][ni][r] + bv;
      }
    }
  } else {
#pragma unroll
    for (int mi = 0; mi < 4; mi++) {
#pragma unroll
      for (int r = 0; r < 4; r++) {
        const size_t t = m0 + wr * 64 + mi * 16 + rowgrp + r;
        ushort_t* rowp = out_qkv + t * 1536;
#pragma unroll
        for (int ni = 0; ni < 4; ni++) {
          const int o = o0 + wc * 64 + ni * 16 + colbase;
          rowp[o] = f2bf(acc[mi][ni][r] + bias[o]);
        }
      }
    }
  }
}

// ---------------------------------------------------------------------------
// Attention (R13-proven): wave-per-head, token-major qkv, wave-private LDS,
// quarter Ps, maskx float4, no-max softmax + ones-MFMA rowsum, mem-order
// fences only.
// ---------------------------------------------------------------------------
__global__ __launch_bounds__(256) void k_attn4(const ushort_t* __restrict__ qkv,
                                               const float* __restrict__ maskx,
                                               ushort_t* __restrict__ aout) {
  __shared__ __align__(16) ushort_t Vt[4][32][64];   // per-wave V^T (swizzled)
  __shared__ __align__(16) ushort_t Ps[4][16][64];   // per-wave P quarter-tile

  const int tid  = threadIdx.x;
  const int lane = tid & 63;
  const int wv   = tid >> 6;
  const int blk  = blockIdx.x;
  const int b    = blk >> 2;
  const int h    = (blk & 3) * 4 + wv;
  const int w    = b & 63;
  const size_t tb = (size_t)b * 49 * 1536 + (size_t)h * 32;
  const ushort_t* qb = qkv + tb;          // + n*1536 + d
  const ushort_t* kb = qkv + tb + 512;
  const ushort_t* vb = qkv + tb + 1024;

  {
    uint4* vz = reinterpret_cast<uint4*>(&Vt[wv][0][0]);
#pragma unroll
    for (int i = 0; i < 4; i++) vz[i * 64 + lane] = make_uint4(0, 0, 0, 0);
  }
#pragma unroll
  for (int i = 0; i < 4; i++) {
    const int e = lane + (i << 6);
    if (e < 196) {
      const int n = e >> 2, d0 = (e & 3) * 8;
      uint4 raw = *reinterpret_cast<const uint4*>(vb + (size_t)n * 1536 + d0);
      us8 ev = __builtin_bit_cast(us8, raw);
#pragma unroll
      for (int j = 0; j < 8; j++)
        Vt[wv][d0 + j][(((n >> 3) ^ j) << 3) | (n & 7)] = ev[j];
    }
  }
  lds_fence();   // Vt writes -> vf reads (wave-local)

  const int arow = lane & 15;
  const int kc   = (lane >> 4) * 8;
  const int rg   = (lane >> 4) * 4;
  const float* mxb = maskx + ((size_t)w * 64 + rg) * 16 * 4 + (size_t)arow * 4;

  uint4 vf0[2], vf1[2];
#pragma unroll
  for (int kk = 0; kk < 2; kk++) {
    const int ch = kk * 4 + (lane >> 4);
    const int cb = ((ch ^ (lane & 7)) << 3);
    vf0[kk] = *reinterpret_cast<const uint4*>(&Vt[wv][arow][cb]);
    vf1[kk] = *reinterpret_cast<const uint4*>(&Vt[wv][16 + arow][cb]);
  }

  uint4 kf[4];
#pragma unroll
  for (int ni = 0; ni < 4; ni++)
    kf[ni] = *reinterpret_cast<const uint4*>(kb + (size_t)(ni * 16 + arow) * 1536 + kc);

  bf16x8 ones;
#pragma unroll
  for (int i = 0; i < 8; i++) ones[i] = (__bf16)1.0f;

#pragma unroll
  for (int mt = 0; mt < 4; mt++) {
    {
      uint4 qraw = *reinterpret_cast<const uint4*>(qb + (size_t)(mt * 16 + arow) * 1536 + kc);
      bf16x8 qa = __builtin_bit_cast(bf16x8, qraw);
      f32x4 s[4];
#pragma unroll
      for (int ni = 0; ni < 4; ni++) {
        f32x4 z = {0.f, 0.f, 0.f, 0.f};
        s[ni] = __builtin_amdgcn_mfma_f32_16x16x32_bf16(
            qa, __builtin_bit_cast(bf16x8, kf[ni]), z, 0, 0, 0);
      }
#pragma unroll
      for (int r = 0; r < 4; r++) {
        const int prow = rg + r;
        f32x4 mv = *reinterpret_cast<const f32x4*>(mxb + ((size_t)mt * 16 + r) * 64);
#pragma unroll
        for (int ni = 0; ni < 4; ni++) {
          const float p = __expf(s[ni][r] + mv[ni]);   // q pre-scaled; pad->0
          const int pcol = ni * 16 + arow;
          Ps[wv][prow][(((pcol >> 3) ^ (prow & 7)) << 3) | (pcol & 7)] = f2bf(p);
        }
      }
    }
    lds_fence();   // Ps writes -> Ps reads (wave-local RAW)

    {
      f32x4 o0 = {0.f, 0.f, 0.f, 0.f}, o1 = {0.f, 0.f, 0.f, 0.f};
      f32x4 o2 = {0.f, 0.f, 0.f, 0.f};
#pragma unroll
      for (int kk = 0; kk < 2; kk++) {
        const int ch = kk * 4 + (lane >> 4);
        const int cb = ((ch ^ (lane & 7)) << 3);
        uint4 praw = *reinterpret_cast<const uint4*>(&Ps[wv][arow][cb]);
        bf16x8 pa = __builtin_bit_cast(bf16x8, praw);
        o0 = __builtin_amdgcn_mfma_f32_16x16x32_bf16(
            pa, __builtin_bit_cast(bf16x8, vf0[kk]), o0, 0, 0, 0);
        o1 = __builtin_amdgcn_mfma_f32_16x16x32_bf16(
            pa, __builtin_bit_cast(bf16x8, vf1[kk]), o1, 0, 0, 0);
        o2 = __builtin_amdgcn_mfma_f32_16x16x32_bf16(pa, ones, o2, 0, 0, 0);
      }
#pragma unroll
      for (int r = 0; r < 4; r++) {
        const int qr = mt * 16 + rg + r;
        if (qr < 49) {
          const float inv = 1.f / o2[r];
          aout[((size_t)b * 49 + qr) * 512 + h * 32 + arow]      = f2bf(o0[r] * inv);
          aout[((size_t)b * 49 + qr) * 512 + h * 32 + 16 + arow] = f2bf(o1[r] * inv);
        }
      }
    }
    lds_fence();   // Ps reads done -> next-mt writes may land (wave-local WAR)
  }
}

// ---------------------------------------------------------------------------
// launch
// ---------------------------------------------------------------------------
extern "C" void kernel_launch(void* const* d_in, const int* in_sizes, int n_in,
                              void* d_out, int out_size, void* d_ws, size_t ws_size,
                              hipStream_t stream) {
  const float* x      = (const float*)d_in[0];
  const float* mask   = (const float*)d_in[1];
  const float* W_qkv  = (const float*)d_in[2];
  const float* b_qkv  = (const float*)d_in[3];
  const float* W_proj = (const float*)d_in[4];
  const float* b_proj = (const float*)d_in[5];
  float* out = (float*)d_out;

  // ws layout (bf16 elems): xb | qkv token-major | attn_out | Wqkv_b | Wproj_b
  // | maskx (f32 262144) | bscaled (f32 1536)
  ushort_t* ws     = (ushort_t*)d_ws;
  ushort_t* xb     = ws;                                  // 51,380,224
  ushort_t* qkvb   = ws + 51380224UL;                     // 154,140,672
  ushort_t* aoutb  = ws + 205520896UL;                    // 51,380,224
  ushort_t* wqkvb  = ws + 256901120UL;                    // 786,432
  ushort_t* wprojb = ws + 257687552UL;                    // 262,144
  float*    maskxb = (float*)(ws + 257949696UL);          // 262,144 f32
  float*    bscale = (float*)(ws + 258473984UL);          // 1,536 f32

  const int n4x = 51380224 / 4, n4q = 786432 / 4, n4p = 262144 / 4;
  k_cvt<<<(n4x + 255) / 256, 256, 0, stream>>>(x, xb, n4x);
  k_cvtwq<<<(n4q + 255) / 256, 256, 0, stream>>>(W_qkv, wqkvb, n4q);
  k_cvt<<<(n4p + 255) / 256, 256, 0, stream>>>(W_proj, wprojb, n4p);
  k_bs<<<6, 256, 0, stream>>>(b_qkv, bscale);
  k_maskx<<<262144 / 256, 256, 0, stream>>>(mask, maskxb);

  // GEMM1: [100352,512] x [1536,512]^T -> token-major qkv (q pre-scaled).
  k_gemm<0><<<784 * 12, 256, 0, stream>>>(xb, wqkvb, bscale, qkvb, nullptr, 12);

  // attention: block = 4 heads, wave = 1 head
  k_attn4<<<2048 * 4, 256, 0, stream>>>(qkvb, maskxb, aoutb);

  // GEMM2: [100352,512] x [512,512]^T + bias -> fp32 out.
  k_gemm<1><<<784 * 4, 256, 0, stream>>>(aoutb, wprojb, b_proj, nullptr, out, 4);
}

// Round 16
// 545.433 us; speedup vs baseline: 1.0450x; 1.0450x over previous
//
#include <hip/hip_runtime.h>

// ---------------------------------------------------------------------------
// WindowAttention: x[2048,49,512] fp32 -> out[2048,49,512] fp32
// R1: T2 LDS XOR-swizzle + T1 XCD swizzle (bank conflicts -> 0).   [593us]
// R2/R5/R11/R14: GEMM restructures (8-phase 256^2, counted-vmcnt dbuf,
//     256x128 8-wave, BK=32) ALL neutral-or-worse at K=512. R14's BK=32
//     swizzle had 1.9e7 measured conflicts -> swizzle claims need byte-level
//     bank arithmetic. R1/R13 BK=64 structure is the operating point.
// R3: raw-barrier RACE. R4/R7: fused cvt REGRESSED.
// R6: wave-per-head attention.                                     [575us]
// R8: no-max softmax + ones-MFMA rowsum; token-major qkv.          [573us]
// R9/R10: attn wave-private LDS, no syncthreads, quarter Ps.       [554us]
// R12: maskx float4; scale-in-epilogue branch cost 15us.
// R13: scale folded into W/bias at cvt; attn fence = mem-order only.[542us]
// R15: REVERT to R13-proven bits (best measured).
// ---------------------------------------------------------------------------

typedef unsigned short ushort_t;
typedef __bf16 bf16x8 __attribute__((ext_vector_type(8)));
typedef float f32x4 __attribute__((ext_vector_type(4)));
typedef unsigned short us8 __attribute__((ext_vector_type(8)));

#define SCALE_F 0.17677669529663687f   // 32^-0.5

// RNE float -> bf16 (as raw ushort)
__device__ __forceinline__ ushort_t f2bf(float f) {
  unsigned u = __builtin_bit_cast(unsigned, f);
  u += 0x7FFFu + ((u >> 16) & 1u);
  return (ushort_t)(u >> 16);
}

// async global->LDS, 16B per lane; lds base must be wave-uniform
__device__ __forceinline__ void gload_lds16(const void* g, void* l) {
  __builtin_amdgcn_global_load_lds(
      (const __attribute__((address_space(1))) void*)g,
      (__attribute__((address_space(3))) void*)l, 16, 0, 0);
}

// wave-local LDS ordering fence: drains DS ops + compiler memory order.
// NO sched_barrier: scheduler may overlap unrelated VALU/VMEM across it.
__device__ __forceinline__ void lds_fence() {
  asm volatile("s_waitcnt lgkmcnt(0)" ::: "memory");
}

// ---------------------------------------------------------------------------
// fp32 -> bf16 conversion, 4 elems/thread
// ---------------------------------------------------------------------------
__global__ __launch_bounds__(256) void k_cvt(const float* __restrict__ in,
                                             ushort_t* __restrict__ out, int n4) {
  int i = blockIdx.x * blockDim.x + threadIdx.x;
  if (i >= n4) return;
  float4 v = reinterpret_cast<const float4*>(in)[i];
  ushort4 o = make_ushort4(f2bf(v.x), f2bf(v.y), f2bf(v.z), f2bf(v.w));
  reinterpret_cast<ushort4*>(out)[i] = o;
}

// W_qkv cvt with q-row pre-scale: rows o<512 (elems < 262144) * SCALE_F.
__global__ __launch_bounds__(256) void k_cvtwq(const float* __restrict__ in,
                                               ushort_t* __restrict__ out, int n4) {
  int i = blockIdx.x * blockDim.x + threadIdx.x;
  if (i >= n4) return;
  const float sc = (i < (262144 / 4)) ? SCALE_F : 1.0f;
  float4 v = reinterpret_cast<const float4*>(in)[i];
  ushort4 o = make_ushort4(f2bf(v.x * sc), f2bf(v.y * sc),
                           f2bf(v.z * sc), f2bf(v.w * sc));
  reinterpret_cast<ushort4*>(out)[i] = o;
}

// scaled qkv bias: bs[i] = b[i] * (i<512 ? SCALE : 1). 1536 elems.
__global__ __launch_bounds__(256) void k_bs(const float* __restrict__ b,
                                            float* __restrict__ bs) {
  int i = blockIdx.x * blockDim.x + threadIdx.x;
  if (i < 1536) bs[i] = b[i] * (i < 512 ? SCALE_F : 1.0f);
}

// ---------------------------------------------------------------------------
// mask pre-transpose: maskx[w][qr(64)][arow(16)][ni(4)] f32, pad = -100.
// ---------------------------------------------------------------------------
__global__ __launch_bounds__(256) void k_maskx(const float* __restrict__ mask,
                                               float* __restrict__ maskx) {
  const int i = blockIdx.x * blockDim.x + threadIdx.x;   // < 262144
  const int ni = i & 3, arow = (i >> 2) & 15, qr = (i >> 6) & 63, w = i >> 12;
  const int col = ni * 16 + arow;
  float v = -100.0f;
  if (qr < 49 && col < 49) v = mask[((size_t)w * 49 + qr) * 49 + col];
  maskx[i] = v;
}

// ---------------------------------------------------------------------------
// GEMM1 (R13-proven): qkv[t][o] = sum_k A[t][k]*W[o][k] + bs[o]
// (q pre-scaled via W/bias). 128x128 tile, BK=64, 4 waves, gload_lds,
// XOR-swizzled LDS (slot(row,c) holds chunk c^(row&7), pre-swizzled source),
// token-major coalesced epilogue.
// ---------------------------------------------------------------------------
__global__ __launch_bounds__(256) void k_gemm1(const ushort_t* __restrict__ A,
                                               const ushort_t* __restrict__ W,
                                               const float* __restrict__ bias,
                                               ushort_t* __restrict__ out_qkv) {
  __shared__ __align__(16) ushort_t As[128][64];
  __shared__ __align__(16) ushort_t Ws[128][64];
  constexpr int nt_o = 12;

  const int tid  = threadIdx.x;
  const int lane = tid & 63;
  const int wv   = tid >> 6;
  const int wr   = wv >> 1, wc = wv & 1;

  const int cpx = gridDim.x >> 3;
  const int lid = (blockIdx.x & 7) * cpx + (blockIdx.x >> 3);
  const int bm  = lid / nt_o;
  const int bo  = lid - bm * nt_o;
  const size_t m0 = (size_t)bm * 128;
  const int o0    = bo * 128;

  f32x4 acc[4][4];
#pragma unroll
  for (int i = 0; i < 4; i++)
#pragma unroll
    for (int j = 0; j < 4; j++) acc[i][j] = f32x4{0.f, 0.f, 0.f, 0.f};

  const int srow   = wv * 32 + (lane >> 3);
  const int schunk = (((lane & 7) ^ (lane >> 3)) * 8);

  for (int kt = 0; kt < 8; ++kt) {
    const int k0 = kt * 64;
#pragma unroll
    for (int i = 0; i < 4; i++)
      gload_lds16(A + (m0 + srow + i * 8) * 512 + k0 + schunk,
                  &As[wv * 32 + i * 8][0]);
#pragma unroll
    for (int i = 0; i < 4; i++)
      gload_lds16(W + (size_t)(o0 + srow + i * 8) * 512 + k0 + schunk,
                  &Ws[wv * 32 + i * 8][0]);
    __syncthreads();
    const int fr = lane & 15;
#pragma unroll
    for (int kk = 0; kk < 2; ++kk) {
      const int ch = kk * 4 + (lane >> 4);
      const int cb = ((ch ^ (lane & 7)) << 3);
      uint4 ar[4], br[4];
#pragma unroll
      for (int mi = 0; mi < 4; mi++)
        ar[mi] = *reinterpret_cast<const uint4*>(&As[wr * 64 + mi * 16 + fr][cb]);
#pragma unroll
      for (int ni = 0; ni < 4; ni++)
        br[ni] = *reinterpret_cast<const uint4*>(&Ws[wc * 64 + ni * 16 + fr][cb]);
#pragma unroll
      for (int mi = 0; mi < 4; mi++)
#pragma unroll
        for (int ni = 0; ni < 4; ni++)
          acc[mi][ni] = __builtin_amdgcn_mfma_f32_16x16x32_bf16(
              __builtin_bit_cast(bf16x8, ar[mi]),
              __builtin_bit_cast(bf16x8, br[ni]), acc[mi][ni], 0, 0, 0);
    }
    __syncthreads();
  }

  const int colbase = lane & 15;
  const int rowgrp  = (lane >> 4) * 4;
#pragma unroll
  for (int mi = 0; mi < 4; mi++) {
#pragma unroll
    for (int r = 0; r < 4; r++) {
      const size_t t = m0 + wr * 64 + mi * 16 + rowgrp + r;
      ushort_t* rowp = out_qkv + t * 1536;
#pragma unroll
      for (int ni = 0; ni < 4; ni++) {
        const int o = o0 + wc * 64 + ni * 16 + colbase;
        rowp[o] = f2bf(acc[mi][ni][r] + bias[o]);
      }
    }
  }
}

// ---------------------------------------------------------------------------
// GEMM2 (R13-proven): out[m][o] = sum_k A[m][k]*W[o][k] + bias[o], fp32 out.
// ---------------------------------------------------------------------------
__global__ __launch_bounds__(256) void k_gemmB(const ushort_t* __restrict__ A,
                                               const ushort_t* __restrict__ W,
                                               const float* __restrict__ bias,
                                               float* __restrict__ out_f,
                                               int nt_o) {
  __shared__ __align__(16) ushort_t As[128][64];
  __shared__ __align__(16) ushort_t Ws[128][64];

  const int tid  = threadIdx.x;
  const int lane = tid & 63;
  const int wv   = tid >> 6;
  const int wr   = wv >> 1, wc = wv & 1;

  const int cpx = gridDim.x >> 3;
  const int lid = (blockIdx.x & 7) * cpx + (blockIdx.x >> 3);
  const int bm  = lid / nt_o;
  const int bo  = lid - bm * nt_o;
  const size_t m0 = (size_t)bm * 128;
  const int o0    = bo * 128;

  f32x4 acc[4][4];
#pragma unroll
  for (int i = 0; i < 4; i++)
#pragma unroll
    for (int j = 0; j < 4; j++) acc[i][j] = f32x4{0.f, 0.f, 0.f, 0.f};

  const int srow   = wv * 32 + (lane >> 3);
  const int schunk = (((lane & 7) ^ (lane >> 3)) * 8);

  for (int kt = 0; kt < 8; ++kt) {
    const int k0 = kt * 64;
#pragma unroll
    for (int i = 0; i < 4; i++)
      gload_lds16(A + (m0 + srow + i * 8) * 512 + k0 + schunk,
                  &As[wv * 32 + i * 8][0]);
#pragma unroll
    for (int i = 0; i < 4; i++)
      gload_lds16(W + (size_t)(o0 + srow + i * 8) * 512 + k0 + schunk,
                  &Ws[wv * 32 + i * 8][0]);
    __syncthreads();
    const int fr = lane & 15;
#pragma unroll
    for (int kk = 0; kk < 2; ++kk) {
      const int ch = kk * 4 + (lane >> 4);
      const int cb = ((ch ^ (lane & 7)) << 3);
      uint4 ar[4], br[4];
#pragma unroll
      for (int mi = 0; mi < 4; mi++)
        ar[mi] = *reinterpret_cast<const uint4*>(&As[wr * 64 + mi * 16 + fr][cb]);
#pragma unroll
      for (int ni = 0; ni < 4; ni++)
        br[ni] = *reinterpret_cast<const uint4*>(&Ws[wc * 64 + ni * 16 + fr][cb]);
#pragma unroll
      for (int mi = 0; mi < 4; mi++)
#pragma unroll
        for (int ni = 0; ni < 4; ni++)
          acc[mi][ni] = __builtin_amdgcn_mfma_f32_16x16x32_bf16(
              __builtin_bit_cast(bf16x8, ar[mi]),
              __builtin_bit_cast(bf16x8, br[ni]), acc[mi][ni], 0, 0, 0);
    }
    __syncthreads();
  }

  const int colbase = lane & 15;
  const int rowgrp  = (lane >> 4) * 4;
#pragma unroll
  for (int ni = 0; ni < 4; ni++) {
    const int o = o0 + wc * 64 + ni * 16 + colbase;
    const float bv = bias[o];
#pragma unroll
    for (int mi = 0; mi < 4; mi++) {
      const size_t mrow = m0 + wr * 64 + mi * 16 + rowgrp;
#pragma unroll
      for (int r = 0; r < 4; r++)
        out_f[(mrow + r) * 512 + o] = acc[mi][ni][r] + bv;
    }
  }
}

// ---------------------------------------------------------------------------
// Attention (R13-proven): wave-per-head, token-major qkv, wave-private LDS,
// quarter Ps, maskx float4, no-max softmax + ones-MFMA rowsum, mem-order
// fences only.
// ---------------------------------------------------------------------------
__global__ __launch_bounds__(256) void k_attn4(const ushort_t* __restrict__ qkv,
                                               const float* __restrict__ maskx,
                                               ushort_t* __restrict__ aout) {
  __shared__ __align__(16) ushort_t Vt[4][32][64];   // per-wave V^T (swizzled)
  __shared__ __align__(16) ushort_t Ps[4][16][64];   // per-wave P quarter-tile

  const int tid  = threadIdx.x;
  const int lane = tid & 63;
  const int wv   = tid >> 6;
  const int blk  = blockIdx.x;
  const int b    = blk >> 2;
  const int h    = (blk & 3) * 4 + wv;
  const int w    = b & 63;
  const size_t tb = (size_t)b * 49 * 1536 + (size_t)h * 32;
  const ushort_t* qb = qkv + tb;          // + n*1536 + d
  const ushort_t* kb = qkv + tb + 512;
  const ushort_t* vb = qkv + tb + 1024;

  {
    uint4* vz = reinterpret_cast<uint4*>(&Vt[wv][0][0]);
#pragma unroll
    for (int i = 0; i < 4; i++) vz[i * 64 + lane] = make_uint4(0, 0, 0, 0);
  }
#pragma unroll
  for (int i = 0; i < 4; i++) {
    const int e = lane + (i << 6);
    if (e < 196) {
      const int n = e >> 2, d0 = (e & 3) * 8;
      uint4 raw = *reinterpret_cast<const uint4*>(vb + (size_t)n * 1536 + d0);
      us8 ev = __builtin_bit_cast(us8, raw);
#pragma unroll
      for (int j = 0; j < 8; j++)
        Vt[wv][d0 + j][(((n >> 3) ^ j) << 3) | (n & 7)] = ev[j];
    }
  }
  lds_fence();   // Vt writes -> vf reads (wave-local)

  const int arow = lane & 15;
  const int kc   = (lane >> 4) * 8;
  const int rg   = (lane >> 4) * 4;
  const float* mxb = maskx + ((size_t)w * 64 + rg) * 16 * 4 + (size_t)arow * 4;

  uint4 vf0[2], vf1[2];
#pragma unroll
  for (int kk = 0; kk < 2; kk++) {
    const int ch = kk * 4 + (lane >> 4);
    const int cb = ((ch ^ (lane & 7)) << 3);
    vf0[kk] = *reinterpret_cast<const uint4*>(&Vt[wv][arow][cb]);
    vf1[kk] = *reinterpret_cast<const uint4*>(&Vt[wv][16 + arow][cb]);
  }

  uint4 kf[4];
#pragma unroll
  for (int ni = 0; ni < 4; ni++)
    kf[ni] = *reinterpret_cast<const uint4*>(kb + (size_t)(ni * 16 + arow) * 1536 + kc);

  bf16x8 ones;
#pragma unroll
  for (int i = 0; i < 8; i++) ones[i] = (__bf16)1.0f;

#pragma unroll
  for (int mt = 0; mt < 4; mt++) {
    // ---- S for this mt, exp, store into quarter buffer (branch-free) ----
    {
      uint4 qraw = *reinterpret_cast<const uint4*>(qb + (size_t)(mt * 16 + arow) * 1536 + kc);
      bf16x8 qa = __builtin_bit_cast(bf16x8, qraw);
      f32x4 s[4];
#pragma unroll
      for (int ni = 0; ni < 4; ni++) {
        f32x4 z = {0.f, 0.f, 0.f, 0.f};
        s[ni] = __builtin_amdgcn_mfma_f32_16x16x32_bf16(
            qa, __builtin_bit_cast(bf16x8, kf[ni]), z, 0, 0, 0);
      }
#pragma unroll
      for (int r = 0; r < 4; r++) {
        const int prow = rg + r;
        f32x4 mv = *reinterpret_cast<const f32x4*>(mxb + ((size_t)mt * 16 + r) * 64);
#pragma unroll
        for (int ni = 0; ni < 4; ni++) {
          const float p = __expf(s[ni][r] + mv[ni]);   // q pre-scaled; pad->0
          const int pcol = ni * 16 + arow;
          Ps[wv][prow][(((pcol >> 3) ^ (prow & 7)) << 3) | (pcol & 7)] = f2bf(p);
        }
      }
    }
    lds_fence();   // Ps writes -> Ps reads (wave-local RAW)

    // ---- PV for this mt (+ ones-MFMA rowsum) ----
    {
      f32x4 o0 = {0.f, 0.f, 0.f, 0.f}, o1 = {0.f, 0.f, 0.f, 0.f};
      f32x4 o2 = {0.f, 0.f, 0.f, 0.f};
#pragma unroll
      for (int kk = 0; kk < 2; kk++) {
        const int ch = kk * 4 + (lane >> 4);
        const int cb = ((ch ^ (lane & 7)) << 3);
        uint4 praw = *reinterpret_cast<const uint4*>(&Ps[wv][arow][cb]);
        bf16x8 pa = __builtin_bit_cast(bf16x8, praw);
        o0 = __builtin_amdgcn_mfma_f32_16x16x32_bf16(
            pa, __builtin_bit_cast(bf16x8, vf0[kk]), o0, 0, 0, 0);
        o1 = __builtin_amdgcn_mfma_f32_16x16x32_bf16(
            pa, __builtin_bit_cast(bf16x8, vf1[kk]), o1, 0, 0, 0);
        o2 = __builtin_amdgcn_mfma_f32_16x16x32_bf16(pa, ones, o2, 0, 0, 0);
      }
#pragma unroll
      for (int r = 0; r < 4; r++) {
        const int qr = mt * 16 + rg + r;
        if (qr < 49) {
          const float inv = 1.f / o2[r];
          aout[((size_t)b * 49 + qr) * 512 + h * 32 + arow]      = f2bf(o0[r] * inv);
          aout[((size_t)b * 49 + qr) * 512 + h * 32 + 16 + arow] = f2bf(o1[r] * inv);
        }
      }
    }
    lds_fence();   // Ps reads done -> next-mt writes may land (wave-local WAR)
  }
}

// ---------------------------------------------------------------------------
// launch
// ---------------------------------------------------------------------------
extern "C" void kernel_launch(void* const* d_in, const int* in_sizes, int n_in,
                              void* d_out, int out_size, void* d_ws, size_t ws_size,
                              hipStream_t stream) {
  const float* x      = (const float*)d_in[0];
  const float* mask   = (const float*)d_in[1];
  const float* W_qkv  = (const float*)d_in[2];
  const float* b_qkv  = (const float*)d_in[3];
  const float* W_proj = (const float*)d_in[4];
  const float* b_proj = (const float*)d_in[5];
  float* out = (float*)d_out;

  // ws layout (bf16 elems): xb | qkv token-major | attn_out | Wqkv_b | Wproj_b
  // | maskx (f32 262144) | bscaled (f32 1536)
  ushort_t* ws     = (ushort_t*)d_ws;
  ushort_t* xb     = ws;                                  // 51,380,224
  ushort_t* qkvb   = ws + 51380224UL;                     // 154,140,672
  ushort_t* aoutb  = ws + 205520896UL;                    // 51,380,224
  ushort_t* wqkvb  = ws + 256901120UL;                    // 786,432
  ushort_t* wprojb = ws + 257687552UL;                    // 262,144
  float*    maskxb = (float*)(ws + 257949696UL);          // 262,144 f32
  float*    bscale = (float*)(ws + 258473984UL);          // 1,536 f32

  const int n4x = 51380224 / 4, n4q = 786432 / 4, n4p = 262144 / 4;
  k_cvt<<<(n4x + 255) / 256, 256, 0, stream>>>(x, xb, n4x);
  k_cvtwq<<<(n4q + 255) / 256, 256, 0, stream>>>(W_qkv, wqkvb, n4q);
  k_cvt<<<(n4p + 255) / 256, 256, 0, stream>>>(W_proj, wprojb, n4p);
  k_bs<<<6, 256, 0, stream>>>(b_qkv, bscale);
  k_maskx<<<262144 / 256, 256, 0, stream>>>(mask, maskxb);

  // GEMM1: [100352,512] x [1536,512]^T -> token-major qkv (q pre-scaled).
  k_gemm1<<<784 * 12, 256, 0, stream>>>(xb, wqkvb, bscale, qkvb);

  // attention: block = 4 heads, wave = 1 head
  k_attn4<<<2048 * 4, 256, 0, stream>>>(qkvb, maskxb, aoutb);

  // GEMM2: [100352,512] x [512,512]^T + bias -> fp32 out.
  k_gemmB<<<784 * 4, 256, 0, stream>>>(aoutb, wprojb, b_proj, out, 4);
}